// Round 5
// baseline (493.985 us; speedup 1.0000x reference)
//
#include <hip/hip_runtime.h>
#include <hip/hip_bf16.h>
#include <stdint.h>

typedef unsigned short u16;
typedef __attribute__((ext_vector_type(8))) short short8;
typedef __attribute__((ext_vector_type(4))) short short4v;
typedef __attribute__((ext_vector_type(4))) float float4v;

// RNE float->bf16
__device__ __forceinline__ u16 f2bf(float x) {
    union { float f; unsigned int u; } v; v.f = x;
    unsigned int r = v.u + 0x7fffu + ((v.u >> 16) & 1u);
    return (u16)(r >> 16);
}

__device__ __forceinline__ void ld_g2l16(const void* g, void* l) {
    __builtin_amdgcn_global_load_lds(
        (const __attribute__((address_space(1))) void*)g,
        (__attribute__((address_space(3))) void*)l, 16, 0, 0);
}

__device__ __forceinline__ void atomic_add_f32(float* p, float v) {
#if defined(__gfx90a__) || defined(__gfx940__) || defined(__gfx941__) || defined(__gfx942__) || defined(__gfx950__)
    unsafeAtomicAdd(p, v);
#else
    atomicAdd(p, v);
#endif
}

// ---------------- Pass 1: tables -> bf16 (coalesced, 1 float4/thread) + pack W1 --
// W1pack[kc][t][lane][j] = W1[kc*32 + (lane>>4)*8 + j][t*16 + (lane&15)]
__global__ __launch_bounds__(256) void conv_pack(
    const float* __restrict__ zs, const float* __restrict__ zt,
    const float* __restrict__ W1,
    u16* __restrict__ zs_b, u16* __restrict__ zt_b, u16* __restrict__ w1p,
    int n4s, int n4t)
{
    int id = blockIdx.x * 256 + threadIdx.x;
    int n4 = n4s + n4t;
    if (id < n4) {
        const float4* src; u16* dst; int i;
        if (id < n4s) { src = (const float4*)zs; dst = zs_b; i = id; }
        else          { src = (const float4*)zt; dst = zt_b; i = id - n4s; }
        float4 a = src[i];
        short4v o;
        o[0] = (short)f2bf(a.x); o[1] = (short)f2bf(a.y);
        o[2] = (short)f2bf(a.z); o[3] = (short)f2bf(a.w);
        *(short4v*)(dst + (size_t)i * 4) = o;
    } else {
        int w = id - n4;
        if (w < 4096) {
            int lanep = w & 63, t = (w >> 6) & 7, kc = w >> 9;
            short8 o;
#pragma unroll
            for (int j = 0; j < 8; ++j) {
                int k = kc * 32 + (lanep >> 4) * 8 + j;
                int n = t * 16 + (lanep & 15);
                o[j] = (short)f2bf(W1[k * 128 + n]);
            }
            *(short8*)(w1p + (size_t)w * 8) = o;
        }
    }
}

// A-frag gather: lane m15 = edge-in-group, quad = 16B k-offset
__device__ __forceinline__ short8 loadA(
    const u16* __restrict__ zs, const u16* __restrict__ zt,
    const int* ridx, const int* cidx, int kc, int mtl, int quad)
{
    const u16* base = (kc < 4)
        ? zs + (size_t)(unsigned)ridx[mtl] * 128 + kc * 32
        : zt + (size_t)(unsigned)cidx[mtl] * 128 + (kc - 4) * 32;
    return *(const short8*)(base + quad * 8);
}

// ---------------- Pass 2: nh-split blocks, depth-2 prefetch, barrier-free --------
// Block = 256 thr (4 waves), nh = blockIdx&1 picks which 64-col half of W1 this
// block computes; only that half (32 KB) is staged in LDS -> 3 blocks/CU
// (launch_bounds 256,3 caps VGPR at 170; demand ~150 -> no spill, 12 waves/CU).
// Each wave owns 32-edge tiles (grid-stride): acc[2 mtl][4 j] = 32 AGPR.
// A gathered direct to VGPRs, 4 rotating buffers (issue buf (g+2)&3, compute
// buf g) = depth-2 prefetch = 156 own-cycles of latency coverage per wave.
// Partial W2-dots (2 per edge) combined via HW fp32 atomics on zeroed out.
__global__ __launch_bounds__(256, 3) void edge_mlp(
    const u16* __restrict__ zs, const u16* __restrict__ zt,
    const u16* __restrict__ w1p,
    const int* __restrict__ row, const int* __restrict__ col,
    const float* __restrict__ b1, const float* __restrict__ W2,
    const float* __restrict__ b2, float* __restrict__ out,
    int E, int njobs)
{
    __shared__ u16 Blds[16384];   // 32 KB: this block's n-half of W1, frag layout

    const int tid  = threadIdx.x;
    const int wave = tid >> 6, lane = tid & 63;
    const int m15 = lane & 15, quad = lane >> 4;
    const int nh  = blockIdx.x & 1;
    const int bid = blockIdx.x >> 1;

    // stage this half's 32 frags: local frag c = kc*4+j <-> global frag kc*8+nh*4+j
#pragma unroll
    for (int it = 0; it < 8; ++it) {
        int c = wave * 8 + it;
        int kc = c >> 2, j = c & 3;
        int f = kc * 8 + nh * 4 + j;
        ld_g2l16((const char*)w1p + (size_t)f * 1024 + lane * 16,
                 (char*)Blds + c * 1024);
    }

    // per-lane epilogue params: col = (nh*4+j)*16 + m15
    float b1v[4], w2v[4];
#pragma unroll
    for (int j = 0; j < 4; ++j) {
        b1v[j] = b1[((nh << 2) + j) * 16 + m15];
        w2v[j] = W2[((nh << 2) + j) * 16 + m15];
    }
    const float b2v = (nh == 0) ? b2[0] : 0.f;

    __builtin_amdgcn_s_waitcnt(0);
    __syncthreads();

    const int T = (E + 31) >> 5;
    const int t0 = bid * 4 + wave;
    if (t0 >= T) return;
    const int stride = njobs;

    int ridx[2], cidx[2], nridx[2], ncidx[2];
#pragma unroll
    for (int mtl = 0; mtl < 2; ++mtl) {
        int e = t0 * 32 + mtl * 16 + m15;
        e = e < E ? e : E - 1;
        ridx[mtl] = row[e]; cidx[mtl] = col[e];
    }
    {
        int tn = t0 + stride;
#pragma unroll
        for (int mtl = 0; mtl < 2; ++mtl) {
            int e = tn * 32 + mtl * 16 + m15;
            e = e < E ? e : E - 1;
            nridx[mtl] = row[e]; ncidx[mtl] = col[e];
        }
    }

    // 4 rotating A buffers; preload G0->buf0 (kc 0,1), G1->buf1 (kc 2,3)
    short8 Abuf[4][2][2];   // [buf][kcin][mtl] : 64 VGPRs
#pragma unroll
    for (int b = 0; b < 2; ++b)
#pragma unroll
        for (int kcin = 0; kcin < 2; ++kcin)
#pragma unroll
            for (int mtl = 0; mtl < 2; ++mtl)
                Abuf[b][kcin][mtl] = loadA(zs, zt, ridx, cidx, 2 * b + kcin, mtl, quad);

    for (int t = t0; t < T; t += stride) {
        const int tn = t + stride;
        float4v acc[2][4];
#pragma unroll
        for (int a = 0; a < 2; ++a)
#pragma unroll
            for (int b = 0; b < 4; ++b)
                acc[a][b] = (float4v){0.f, 0.f, 0.f, 0.f};

#pragma unroll
        for (int g = 0; g < 4; ++g) {
            const int ib = (g + 2) & 3;
            if (g < 2) {
                // issue this tile's group g+2 (kc 4..7)
#pragma unroll
                for (int kcin = 0; kcin < 2; ++kcin)
#pragma unroll
                    for (int mtl = 0; mtl < 2; ++mtl)
                        Abuf[ib][kcin][mtl] =
                            loadA(zs, zt, ridx, cidx, 2 * (g + 2) + kcin, mtl, quad);
            } else if (tn < T) {
                // issue next tile's group g-2 (kc 0..3)
#pragma unroll
                for (int kcin = 0; kcin < 2; ++kcin)
#pragma unroll
                    for (int mtl = 0; mtl < 2; ++mtl)
                        Abuf[ib][kcin][mtl] =
                            loadA(zs, zt, nridx, ncidx, 2 * (g - 2) + kcin, mtl, quad);
            }
            // compute group g (buffers issued 2 groups ago)
#pragma unroll
            for (int kcin = 0; kcin < 2; ++kcin) {
                int kc = 2 * g + kcin;
                short8 Bf[4];
#pragma unroll
                for (int j = 0; j < 4; ++j)
                    Bf[j] = *(const short8*)(Blds + (size_t)((kc * 4 + j) * 64 + lane) * 8);
#pragma unroll
                for (int mtl = 0; mtl < 2; ++mtl)
#pragma unroll
                    for (int j = 0; j < 4; ++j)
                        acc[mtl][j] = __builtin_amdgcn_mfma_f32_16x16x32_bf16(
                            Abuf[g][kcin][mtl], Bf[j], acc[mtl][j], 0, 0, 0);
            }
        }

        // roll indices; prefetch t+2*stride
#pragma unroll
        for (int mtl = 0; mtl < 2; ++mtl) {
            ridx[mtl] = nridx[mtl]; cidx[mtl] = ncidx[mtl];
        }
        {
            int tnn = t + 2 * stride;
            if (tnn < T) {
#pragma unroll
                for (int mtl = 0; mtl < 2; ++mtl) {
                    int e = tnn * 32 + mtl * 16 + m15;
                    e = e < E ? e : E - 1;
                    nridx[mtl] = row[e]; ncidx[mtl] = col[e];
                }
            }
        }

        // epilogue: +b1, relu, dot W2 over this n-half, 16-lane butterfly, atomic out
#pragma unroll
        for (int mtl = 0; mtl < 2; ++mtl) {
#pragma unroll
            for (int r = 0; r < 4; ++r) {
                float s = 0.f;
#pragma unroll
                for (int j = 0; j < 4; ++j) {
                    float h = acc[mtl][j][r] + b1v[j];
                    h = h > 0.f ? h : 0.f;
                    s = fmaf(h, w2v[j], s);
                }
                s += __shfl_xor(s, 1);
                s += __shfl_xor(s, 2);
                s += __shfl_xor(s, 4);
                s += __shfl_xor(s, 8);
                if (m15 == 0) {
                    int e = t * 32 + mtl * 16 + quad * 4 + r;
                    if (e < E) atomic_add_f32(out + e, s + b2v);
                }
            }
        }
    }
}

// ---------------- Fallback (fp32, slow but correct) if workspace too small -------
__global__ __launch_bounds__(256) void edge_mlp_naive(
    const float* __restrict__ zs, const float* __restrict__ zt,
    const int* __restrict__ row, const int* __restrict__ col,
    const float* __restrict__ W1, const float* __restrict__ b1,
    const float* __restrict__ W2, const float* __restrict__ b2,
    float* __restrict__ out, int E)
{
    __shared__ float zr[4][256];
    int wave = threadIdx.x >> 6, lane = threadIdx.x & 63;
    int e = blockIdx.x * 4 + wave;
    int ec = e < E ? e : E - 1;
    const float* a = zs + (size_t)row[ec] * 128;
    const float* bb = zt + (size_t)col[ec] * 128;
    zr[wave][lane] = a[lane];
    zr[wave][64 + lane] = a[64 + lane];
    zr[wave][128 + lane] = bb[lane];
    zr[wave][192 + lane] = bb[64 + lane];
    __syncthreads();
    float h0 = b1[lane], h1 = b1[64 + lane];
    for (int k = 0; k < 256; ++k) {
        float zk = zr[wave][k];
        h0 = fmaf(zk, W1[k * 128 + lane], h0);
        h1 = fmaf(zk, W1[k * 128 + 64 + lane], h1);
    }
    h0 = h0 > 0.f ? h0 : 0.f;
    h1 = h1 > 0.f ? h1 : 0.f;
    float s = fmaf(h0, W2[lane], h1 * W2[64 + lane]);
    for (int m = 1; m < 64; m <<= 1) s += __shfl_xor(s, m);
    if (lane == 0 && e < E) out[e] = s + b2[0];
}

extern "C" void kernel_launch(void* const* d_in, const int* in_sizes, int n_in,
                              void* d_out, int out_size, void* d_ws, size_t ws_size,
                              hipStream_t stream) {
    const float* zs = (const float*)d_in[0];
    const float* zt = (const float*)d_in[1];
    const int*  row = (const int*)d_in[2];
    const int*  col = (const int*)d_in[3];
    const float* W1 = (const float*)d_in[4];
    const float* b1 = (const float*)d_in[5];
    const float* W2 = (const float*)d_in[6];
    const float* b2 = (const float*)d_in[7];
    float* out = (float*)d_out;

    const int nzs = in_sizes[0];       // 12,800,000
    const int nzt = in_sizes[1];       // 6,400,000
    const int E   = in_sizes[2];       // 1,000,000

    const size_t need = ((size_t)nzs + (size_t)nzt + 32768) * 2;
    if (ws_size < need) {
        int nb = (E + 3) / 4;
        edge_mlp_naive<<<nb, 256, 0, stream>>>(zs, zt, row, col, W1, b1, W2, b2, out, E);
        return;
    }

    u16* zs_b = (u16*)d_ws;
    u16* zt_b = zs_b + nzs;
    u16* w1p  = zt_b + nzt;

    const int n4s = nzs / 4, n4t = nzt / 4;
    const int convN = n4s + n4t + 4096;
    conv_pack<<<(convN + 255) / 256, 256, 0, stream>>>(zs, zt, W1, zs_b, zt_b, w1p, n4s, n4t);

    // zero the output for atomic accumulation (async on stream: graph-capturable)
    hipMemsetAsync(out, 0, (size_t)E * sizeof(float), stream);

    // 768 blocks = 3/CU (32 KB LDS, launch_bounds(256,3)); blockIdx&1 = n-half;
    // 384 block-pairs x 4 waves = 1536 wave-jobs per n-half grid-striding tiles
    const int nblocks = 768;
    const int njobs = (nblocks / 2) * 4;
    edge_mlp<<<nblocks, 256, 0, stream>>>(zs_b, zt_b, w1p, row, col, b1, W2, b2, out, E, njobs);
}

// Round 6
// 210.451 us; speedup vs baseline: 2.3473x; 2.3473x over previous
//
#include <hip/hip_runtime.h>
#include <hip/hip_bf16.h>
#include <stdint.h>

typedef unsigned short u16;
typedef __attribute__((ext_vector_type(8))) short short8;
typedef __attribute__((ext_vector_type(4))) float float4v;

// RNE float->bf16
__device__ __forceinline__ u16 f2bf(float x) {
    union { float f; unsigned int u; } v; v.f = x;
    unsigned int r = v.u + 0x7fffu + ((v.u >> 16) & 1u);
    return (u16)(r >> 16);
}
__device__ __forceinline__ float bf2f(u16 h) {
    union { unsigned int u; float f; } v; v.u = ((unsigned int)h) << 16;
    return v.f;
}

__device__ __forceinline__ void ld_g2l16(const void* g, void* l) {
    __builtin_amdgcn_global_load_lds(
        (const __attribute__((address_space(1))) void*)g,
        (__attribute__((address_space(3))) void*)l, 16, 0, 0);
}

// ---------------- Pass 0: pack W1 into B-frag layout (tiny) ----------------------
// W1pack[kc][t][lane][j] = W1[kc*32 + (lane>>4)*8 + j][t*16 + (lane&15)]
__global__ __launch_bounds__(256) void w1_pack(
    const float* __restrict__ W1, u16* __restrict__ w1p)
{
    int w = blockIdx.x * 256 + threadIdx.x;   // 0..4095
    int lanep = w & 63, t = (w >> 6) & 7, kc = w >> 9;
    short8 o;
#pragma unroll
    for (int j = 0; j < 8; ++j) {
        int k = kc * 32 + (lanep >> 4) * 8 + j;
        int n = t * 16 + (lanep & 15);
        o[j] = (short)f2bf(W1[k * 128 + n]);
    }
    *(short8*)(w1p + (size_t)w * 8) = o;
}

// ---------------- Pass 1: dense GEMMs U = zs@W1a + b1, V = zt@W1b (bf16 out) -----
// Block = 256 thr, 128x128 output tile, K=128 single shot.
// A staged fp32->bf16 through VGPRs into LDS with per-row XOR chunk swizzle
// (phys chunk q = c ^ (r&15)): MFMA-side ds_read_b128 is 2-way (free).
// B = W1 half in frag layout from w1p (flat 32KB, conflict-free frag reads).
__global__ __launch_bounds__(256) void uv_gemm(
    const float* __restrict__ zs, const float* __restrict__ zt,
    const u16* __restrict__ w1p, const float* __restrict__ b1,
    u16* __restrict__ U, u16* __restrict__ V,
    int M1, int M2, int nU)
{
    __shared__ u16 Alds[16384];   // 32 KB: 128 rows x 128 K (swizzled chunks)
    __shared__ u16 Blds[16384];   // 32 KB: 32 frags of this W1 half

    const int tid = threadIdx.x, wave = tid >> 6, lane = tid & 63;
    const int m15 = lane & 15, quad = lane >> 4;
    const bool isV = (int)blockIdx.x >= nU;
    const float* zsrc = isV ? zt : zs;
    u16* dst = isV ? V : U;
    const int row0 = (isV ? ((int)blockIdx.x - nU) : (int)blockIdx.x) * 128;
    const int M = isV ? M2 : M1;
    const int nrows = (M - row0) < 128 ? (M - row0) : 128;

    // stage B half (32 KB flat): frag f local = kc_local*8+t
    const u16* wsrc = w1p + (isV ? 16384 : 0);
#pragma unroll
    for (int it = 0; it < 8; ++it) {
        int off = (wave * 8 + it) * 1024;
        ld_g2l16((const char*)wsrc + off + lane * 16, (char*)Blds + off);
    }

    // stage A: 128 rows x 16 chunks(16B); lane = (row-in-quad)*16 + phys-chunk q
#pragma unroll
    for (int it = 0; it < 8; ++it) {
        int r = it * 16 + wave * 4 + (lane >> 4);
        int q = lane & 15;
        int c = q ^ (r & 15);                     // logical chunk to fetch
        int rr = r < nrows ? r : (nrows - 1);
        const float4* src = (const float4*)(zsrc + (size_t)(row0 + rr) * 128 + c * 8);
        float4 x = src[0], y = src[1];
        short8 o;
        o[0] = (short)f2bf(x.x); o[1] = (short)f2bf(x.y);
        o[2] = (short)f2bf(x.z); o[3] = (short)f2bf(x.w);
        o[4] = (short)f2bf(y.x); o[5] = (short)f2bf(y.y);
        o[6] = (short)f2bf(y.z); o[7] = (short)f2bf(y.w);
        *(short8*)((char*)Alds + r * 256 + q * 16) = o;
    }

    __builtin_amdgcn_s_waitcnt(0);
    __syncthreads();

    // MFMA: wave owns rows [wave*32, +32) x all 128 n
    float4v acc[2][8];
#pragma unroll
    for (int a = 0; a < 2; ++a)
#pragma unroll
        for (int b = 0; b < 8; ++b)
            acc[a][b] = (float4v){0.f, 0.f, 0.f, 0.f};

#pragma unroll
    for (int kc = 0; kc < 4; ++kc) {
        short8 Af[2];
#pragma unroll
        for (int mtl = 0; mtl < 2; ++mtl) {
            int r = wave * 32 + mtl * 16 + m15;
            int c = kc * 4 + quad;
            int q = c ^ (r & 15);
            Af[mtl] = *(const short8*)((const char*)Alds + r * 256 + q * 16);
        }
#pragma unroll
        for (int t = 0; t < 8; ++t) {
            short8 Bf = *(const short8*)((const char*)Blds + (kc * 8 + t) * 1024 + lane * 16);
#pragma unroll
            for (int mtl = 0; mtl < 2; ++mtl)
                acc[mtl][t] = __builtin_amdgcn_mfma_f32_16x16x32_bf16(
                    Af[mtl], Bf, acc[mtl][t], 0, 0, 0);
        }
    }

    // epilogue: +b1 (U only), round to bf16, store. C/D: col=t*16+m15, row=quad*4+r
#pragma unroll
    for (int t = 0; t < 8; ++t) {
        float bv = isV ? 0.f : b1[t * 16 + m15];
#pragma unroll
        for (int mtl = 0; mtl < 2; ++mtl) {
#pragma unroll
            for (int r = 0; r < 4; ++r) {
                int rr = wave * 32 + mtl * 16 + quad * 4 + r;
                if (rr < nrows)
                    dst[(size_t)(row0 + rr) * 128 + t * 16 + m15] =
                        f2bf(acc[mtl][t][r] + bv);
            }
        }
    }
}

// ---------------- Pass 2: streaming edge decode: relu(U[row]+V[col]).W2 + b2 -----
// 16 lanes per edge (lane m15 owns features [m15*8, m15*8+8)); 128 edges/block.
// All 16 gathers (8 edges x U,V) issued back-to-back per thread: deep MLP,
// 256B coalesced segments, no MFMA coupling, direct stores (no atomics).
__global__ __launch_bounds__(256) void edge_out(
    const u16* __restrict__ U, const u16* __restrict__ V,
    const int* __restrict__ row, const int* __restrict__ col,
    const float* __restrict__ W2, const float* __restrict__ b2,
    float* __restrict__ out, int E)
{
    const int tid = threadIdx.x, m15 = tid & 15, g = tid >> 4;  // 16 groups
    float w2v[8];
#pragma unroll
    for (int j = 0; j < 8; ++j) w2v[j] = W2[m15 * 8 + j];
    const float b2v = b2[0];
    const int e0 = blockIdx.x * 128;

    int ee[8];
#pragma unroll
    for (int it = 0; it < 8; ++it) {
        int e = e0 + it * 16 + g;
        ee[it] = e < E ? e : E - 1;
    }

    short8 uu[8], vv[8];
#pragma unroll
    for (int it = 0; it < 8; ++it) {
        int ri = row[ee[it]];
        int ci = col[ee[it]];
        uu[it] = *(const short8*)(U + (size_t)(unsigned)ri * 128 + m15 * 8);
        vv[it] = *(const short8*)(V + (size_t)(unsigned)ci * 128 + m15 * 8);
    }

#pragma unroll
    for (int it = 0; it < 8; ++it) {
        float s = 0.f;
#pragma unroll
        for (int j = 0; j < 8; ++j) {
            float h = bf2f((u16)uu[it][j]) + bf2f((u16)vv[it][j]);
            h = h > 0.f ? h : 0.f;
            s = fmaf(h, w2v[j], s);
        }
        s += __shfl_xor(s, 1);
        s += __shfl_xor(s, 2);
        s += __shfl_xor(s, 4);
        s += __shfl_xor(s, 8);
        int e = e0 + it * 16 + g;
        if (m15 == 0 && e < E) out[e] = s + b2v;
    }
}

// ---------------- Fallback (fp32, slow but correct) if workspace too small -------
__global__ __launch_bounds__(256) void edge_mlp_naive(
    const float* __restrict__ zs, const float* __restrict__ zt,
    const int* __restrict__ row, const int* __restrict__ col,
    const float* __restrict__ W1, const float* __restrict__ b1,
    const float* __restrict__ W2, const float* __restrict__ b2,
    float* __restrict__ out, int E)
{
    __shared__ float zr[4][256];
    int wave = threadIdx.x >> 6, lane = threadIdx.x & 63;
    int e = blockIdx.x * 4 + wave;
    int ec = e < E ? e : E - 1;
    const float* a = zs + (size_t)row[ec] * 128;
    const float* bb = zt + (size_t)col[ec] * 128;
    zr[wave][lane] = a[lane];
    zr[wave][64 + lane] = a[64 + lane];
    zr[wave][128 + lane] = bb[lane];
    zr[wave][192 + lane] = bb[64 + lane];
    __syncthreads();
    float h0 = b1[lane], h1 = b1[64 + lane];
    for (int k = 0; k < 256; ++k) {
        float zk = zr[wave][k];
        h0 = fmaf(zk, W1[k * 128 + lane], h0);
        h1 = fmaf(zk, W1[k * 128 + 64 + lane], h1);
    }
    h0 = h0 > 0.f ? h0 : 0.f;
    h1 = h1 > 0.f ? h1 : 0.f;
    float s = fmaf(h0, W2[lane], h1 * W2[64 + lane]);
    for (int m = 1; m < 64; m <<= 1) s += __shfl_xor(s, m);
    if (lane == 0 && e < E) out[e] = s + b2[0];
}

extern "C" void kernel_launch(void* const* d_in, const int* in_sizes, int n_in,
                              void* d_out, int out_size, void* d_ws, size_t ws_size,
                              hipStream_t stream) {
    const float* zs = (const float*)d_in[0];
    const float* zt = (const float*)d_in[1];
    const int*  row = (const int*)d_in[2];
    const int*  col = (const int*)d_in[3];
    const float* W1 = (const float*)d_in[4];
    const float* b1 = (const float*)d_in[5];
    const float* W2 = (const float*)d_in[6];
    const float* b2 = (const float*)d_in[7];
    float* out = (float*)d_out;

    const int nzs = in_sizes[0];       // 12,800,000 (100K x 128)
    const int nzt = in_sizes[1];       // 6,400,000  (50K x 128)
    const int E   = in_sizes[2];       // 1,000,000
    const int M1  = nzs / 128;
    const int M2  = nzt / 128;

    const size_t need = ((size_t)nzs + (size_t)nzt + 32768) * 2;
    if (ws_size < need) {
        int nb = (E + 3) / 4;
        edge_mlp_naive<<<nb, 256, 0, stream>>>(zs, zt, row, col, W1, b1, W2, b2, out, E);
        return;
    }

    u16* U   = (u16*)d_ws;             // M1 x 128 bf16
    u16* V   = U + (size_t)nzs;        // M2 x 128 bf16
    u16* w1p = V + (size_t)nzt;        // 64 KB packed W1

    w1_pack<<<16, 256, 0, stream>>>(W1, w1p);

    const int nU = (M1 + 127) / 128;
    const int nV = (M2 + 127) / 128;
    uv_gemm<<<nU + nV, 256, 0, stream>>>(zs, zt, w1p, b1, U, V, M1, M2, nU);

    edge_out<<<(E + 127) / 128, 256, 0, stream>>>(U, V, row, col, W2, b2, out, E);
}

// Round 8
// 210.107 us; speedup vs baseline: 2.3511x; 1.0016x over previous
//
#include <hip/hip_runtime.h>
#include <hip/hip_bf16.h>
#include <stdint.h>

typedef unsigned short u16;
typedef __attribute__((ext_vector_type(8))) short short8;
typedef __attribute__((ext_vector_type(4))) float float4v;
typedef __attribute__((ext_vector_type(2))) _Float16 v2h;

// RNE float->bf16
__device__ __forceinline__ u16 f2bf(float x) {
    union { float f; unsigned int u; } v; v.f = x;
    unsigned int r = v.u + 0x7fffu + ((v.u >> 16) & 1u);
    return (u16)(r >> 16);
}

__device__ __forceinline__ void ld_g2l16(const void* g, void* l) {
    __builtin_amdgcn_global_load_lds(
        (const __attribute__((address_space(1))) void*)g,
        (__attribute__((address_space(3))) void*)l, 16, 0, 0);
}

// packed fp16 dot-accumulate: s += a.x*b.x + a.y*b.y (fp32 acc)
__device__ __forceinline__ float dot2acc(v2h a, v2h b, float s) {
#if __has_builtin(__builtin_amdgcn_fdot2)
    return __builtin_amdgcn_fdot2(a, b, s, false);
#else
    return fmaf((float)a[0], (float)b[0], fmaf((float)a[1], (float)b[1], s));
#endif
}

// ---------------- Pass 0: pack W1 into B-frag layout (tiny) ----------------------
// W1pack[kc][t][lane][j] = W1[kc*32 + (lane>>4)*8 + j][t*16 + (lane&15)]
__global__ __launch_bounds__(256) void w1_pack(
    const float* __restrict__ W1, u16* __restrict__ w1p)
{
    int w = blockIdx.x * 256 + threadIdx.x;   // 0..4095
    int lanep = w & 63, t = (w >> 6) & 7, kc = w >> 9;
    short8 o;
#pragma unroll
    for (int j = 0; j < 8; ++j) {
        int k = kc * 32 + (lanep >> 4) * 8 + j;
        int n = t * 16 + (lanep & 15);
        o[j] = (short)f2bf(W1[k * 128 + n]);
    }
    *(short8*)(w1p + (size_t)w * 8) = o;
}

// ---------------- Pass 1: dense GEMMs U = zs@W1a + b1, V = zt@W1b (fp16 out) -----
// Block = 256 thr, 128x128 output tile, K=128 single shot.
// A staged fp32->bf16 through VGPRs into LDS with per-row XOR chunk swizzle
// (phys chunk q = c ^ (r&15)): MFMA-side ds_read_b128 is 2-way (free).
// B = W1 half in frag layout from w1p (flat 32KB, conflict-free frag reads).
// Output stored as fp16 (finer mantissa than bf16 at |x|<=8; enables packed
// math in edge_out).
__global__ __launch_bounds__(256) void uv_gemm(
    const float* __restrict__ zs, const float* __restrict__ zt,
    const u16* __restrict__ w1p, const float* __restrict__ b1,
    u16* __restrict__ U, u16* __restrict__ V,
    int M1, int M2, int nU)
{
    __shared__ u16 Alds[16384];   // 32 KB: 128 rows x 128 K (swizzled chunks)
    __shared__ u16 Blds[16384];   // 32 KB: 32 frags of this W1 half

    const int tid = threadIdx.x, wave = tid >> 6, lane = tid & 63;
    const int m15 = lane & 15, quad = lane >> 4;
    const bool isV = (int)blockIdx.x >= nU;
    const float* zsrc = isV ? zt : zs;
    u16* dst = isV ? V : U;
    const int row0 = (isV ? ((int)blockIdx.x - nU) : (int)blockIdx.x) * 128;
    const int M = isV ? M2 : M1;
    const int nrows = (M - row0) < 128 ? (M - row0) : 128;

    // stage B half (32 KB flat): frag f local = kc_local*8+t
    const u16* wsrc = w1p + (isV ? 16384 : 0);
#pragma unroll
    for (int it = 0; it < 8; ++it) {
        int off = (wave * 8 + it) * 1024;
        ld_g2l16((const char*)wsrc + off + lane * 16, (char*)Blds + off);
    }

    // stage A: 128 rows x 16 chunks(16B); lane = (row-in-quad)*16 + phys-chunk q
#pragma unroll
    for (int it = 0; it < 8; ++it) {
        int r = it * 16 + wave * 4 + (lane >> 4);
        int q = lane & 15;
        int c = q ^ (r & 15);                     // logical chunk to fetch
        int rr = r < nrows ? r : (nrows - 1);
        const float4* src = (const float4*)(zsrc + (size_t)(row0 + rr) * 128 + c * 8);
        float4 x = src[0], y = src[1];
        short8 o;
        o[0] = (short)f2bf(x.x); o[1] = (short)f2bf(x.y);
        o[2] = (short)f2bf(x.z); o[3] = (short)f2bf(x.w);
        o[4] = (short)f2bf(y.x); o[5] = (short)f2bf(y.y);
        o[6] = (short)f2bf(y.z); o[7] = (short)f2bf(y.w);
        *(short8*)((char*)Alds + r * 256 + q * 16) = o;
    }

    __builtin_amdgcn_s_waitcnt(0);
    __syncthreads();

    // MFMA: wave owns rows [wave*32, +32) x all 128 n
    float4v acc[2][8];
#pragma unroll
    for (int a = 0; a < 2; ++a)
#pragma unroll
        for (int b = 0; b < 8; ++b)
            acc[a][b] = (float4v){0.f, 0.f, 0.f, 0.f};

#pragma unroll
    for (int kc = 0; kc < 4; ++kc) {
        short8 Af[2];
#pragma unroll
        for (int mtl = 0; mtl < 2; ++mtl) {
            int r = wave * 32 + mtl * 16 + m15;
            int c = kc * 4 + quad;
            int q = c ^ (r & 15);
            Af[mtl] = *(const short8*)((const char*)Alds + r * 256 + q * 16);
        }
#pragma unroll
        for (int t = 0; t < 8; ++t) {
            short8 Bf = *(const short8*)((const char*)Blds + (kc * 8 + t) * 1024 + lane * 16);
#pragma unroll
            for (int mtl = 0; mtl < 2; ++mtl)
                acc[mtl][t] = __builtin_amdgcn_mfma_f32_16x16x32_bf16(
                    Af[mtl], Bf, acc[mtl][t], 0, 0, 0);
        }
    }

    // epilogue: +b1 (U only), round to fp16, store. C/D: col=t*16+m15, row=quad*4+r
#pragma unroll
    for (int t = 0; t < 8; ++t) {
        float bv = isV ? 0.f : b1[t * 16 + m15];
#pragma unroll
        for (int mtl = 0; mtl < 2; ++mtl) {
#pragma unroll
            for (int r = 0; r < 4; ++r) {
                int rr = wave * 32 + mtl * 16 + quad * 4 + r;
                if (rr < nrows) {
                    _Float16 h = (_Float16)(acc[mtl][t][r] + bv);
                    union { _Float16 h; u16 u; } cv; cv.h = h;
                    dst[(size_t)(row0 + rr) * 128 + t * 16 + m15] = cv.u;
                }
            }
        }
    }
}

// ---------------- Pass 2: streaming edge decode: relu(U[row]+V[col]).W2 + b2 -----
// 16 lanes per edge (lane m15 owns features [m15*8, m15*8+8)); 128 edges/block.
// All 16 gathers (8 edges x U,V) issued back-to-back per thread, then packed
// fp16 math: v_pk_add_f16 + v_pk_max_f16 + v_dot2_f32_f16 (fp32 accumulate).
// Native _Float16 clang vectors (HIP __half2 intrinsics shadowed by bf16 hdr).
__global__ __launch_bounds__(256) void edge_out(
    const u16* __restrict__ U, const u16* __restrict__ V,
    const int* __restrict__ row, const int* __restrict__ col,
    const float* __restrict__ W2, const float* __restrict__ b2,
    float* __restrict__ out, int E)
{
    const int tid = threadIdx.x, m15 = tid & 15, g = tid >> 4;  // 16 groups
    v2h w2h[4];
#pragma unroll
    for (int j = 0; j < 4; ++j) {
        w2h[j][0] = (_Float16)W2[m15 * 8 + 2 * j];
        w2h[j][1] = (_Float16)W2[m15 * 8 + 2 * j + 1];
    }
    const float b2v = b2[0];
    const v2h zero2 = (v2h){(_Float16)0.f, (_Float16)0.f};
    const int e0 = blockIdx.x * 128;

    int ee[8];
#pragma unroll
    for (int it = 0; it < 8; ++it) {
        int e = e0 + it * 16 + g;
        ee[it] = e < E ? e : E - 1;
    }

    uint4 uu[8], vv[8];
#pragma unroll
    for (int it = 0; it < 8; ++it) {
        int ri = row[ee[it]];
        int ci = col[ee[it]];
        uu[it] = *(const uint4*)(U + (size_t)(unsigned)ri * 128 + m15 * 8);
        vv[it] = *(const uint4*)(V + (size_t)(unsigned)ci * 128 + m15 * 8);
    }

#pragma unroll
    for (int it = 0; it < 8; ++it) {
        float s = 0.f;
        const v2h* uw = (const v2h*)&uu[it];
        const v2h* vw = (const v2h*)&vv[it];
#pragma unroll
        for (int j = 0; j < 4; ++j) {
            v2h h = uw[j] + vw[j];                       // v_pk_add_f16
            h = __builtin_elementwise_max(h, zero2);     // v_pk_max_f16 (relu)
            s = dot2acc(h, w2h[j], s);                   // v_dot2_f32_f16
        }
        s += __shfl_xor(s, 1);
        s += __shfl_xor(s, 2);
        s += __shfl_xor(s, 4);
        s += __shfl_xor(s, 8);
        int e = e0 + it * 16 + g;
        if (m15 == 0 && e < E) out[e] = s + b2v;
    }
}

// ---------------- Fallback (fp32, slow but correct) if workspace too small -------
__global__ __launch_bounds__(256) void edge_mlp_naive(
    const float* __restrict__ zs, const float* __restrict__ zt,
    const int* __restrict__ row, const int* __restrict__ col,
    const float* __restrict__ W1, const float* __restrict__ b1,
    const float* __restrict__ W2, const float* __restrict__ b2,
    float* __restrict__ out, int E)
{
    __shared__ float zr[4][256];
    int wave = threadIdx.x >> 6, lane = threadIdx.x & 63;
    int e = blockIdx.x * 4 + wave;
    int ec = e < E ? e : E - 1;
    const float* a = zs + (size_t)row[ec] * 128;
    const float* bb = zt + (size_t)col[ec] * 128;
    zr[wave][lane] = a[lane];
    zr[wave][64 + lane] = a[64 + lane];
    zr[wave][128 + lane] = bb[lane];
    zr[wave][192 + lane] = bb[64 + lane];
    __syncthreads();
    float h0 = b1[lane], h1 = b1[64 + lane];
    for (int k = 0; k < 256; ++k) {
        float zk = zr[wave][k];
        h0 = fmaf(zk, W1[k * 128 + lane], h0);
        h1 = fmaf(zk, W1[k * 128 + 64 + lane], h1);
    }
    h0 = h0 > 0.f ? h0 : 0.f;
    h1 = h1 > 0.f ? h1 : 0.f;
    float s = fmaf(h0, W2[lane], h1 * W2[64 + lane]);
    for (int m = 1; m < 64; m <<= 1) s += __shfl_xor(s, m);
    if (lane == 0 && e < E) out[e] = s + b2[0];
}

extern "C" void kernel_launch(void* const* d_in, const int* in_sizes, int n_in,
                              void* d_out, int out_size, void* d_ws, size_t ws_size,
                              hipStream_t stream) {
    const float* zs = (const float*)d_in[0];
    const float* zt = (const float*)d_in[1];
    const int*  row = (const int*)d_in[2];
    const int*  col = (const int*)d_in[3];
    const float* W1 = (const float*)d_in[4];
    const float* b1 = (const float*)d_in[5];
    const float* W2 = (const float*)d_in[6];
    const float* b2 = (const float*)d_in[7];
    float* out = (float*)d_out;

    const int nzs = in_sizes[0];       // 12,800,000 (100K x 128)
    const int nzt = in_sizes[1];       // 6,400,000  (50K x 128)
    const int E   = in_sizes[2];       // 1,000,000
    const int M1  = nzs / 128;
    const int M2  = nzt / 128;

    const size_t need = ((size_t)nzs + (size_t)nzt + 32768) * 2;
    if (ws_size < need) {
        int nb = (E + 3) / 4;
        edge_mlp_naive<<<nb, 256, 0, stream>>>(zs, zt, row, col, W1, b1, W2, b2, out, E);
        return;
    }

    u16* U   = (u16*)d_ws;             // M1 x 128 fp16
    u16* V   = U + (size_t)nzs;        // M2 x 128 fp16
    u16* w1p = V + (size_t)nzt;        // 64 KB packed W1 (bf16 frags)

    w1_pack<<<16, 256, 0, stream>>>(W1, w1p);

    const int nU = (M1 + 127) / 128;
    const int nV = (M2 + 127) / 128;
    uv_gemm<<<nU + nV, 256, 0, stream>>>(zs, zt, w1p, b1, U, V, M1, M2, nU);

    edge_out<<<(E + 127) / 128, 256, 0, stream>>>(U, V, row, col, W2, b2, out, E);
}